// Round 1
// baseline (307.461 us; speedup 1.0000x reference)
//
#include <hip/hip_runtime.h>
#include <hip/hip_bf16.h>

// Problem constants (from reference): L layers, B batch, D width.
constexpr int L = 8;
constexpr int B = 32;
constexpr int D = 1280;

constexpr int JT = 64;         // output columns per block
constexpr int ISPLIT = 4;      // i-reduction split across the block's 4 waves
constexpr int BLOCK = JT * ISPLIT;  // 256 threads
constexpr int ICHUNK = D / ISPLIT;  // 320

// One layer: h_out[b,j] = maskrelu( sum_i h_in[b,i]*W[b,i,j] + bias[b,j] )
// grid = (D/JT, B), block = 256.
__global__ __launch_bounds__(BLOCK) void layer_kernel(
    const float* __restrict__ h_in,   // [B, D]
    const float* __restrict__ W,      // [B, D, D]
    const float* __restrict__ bias,   // [B, D]
    const int*   __restrict__ mask,   // [B, D]
    float*       __restrict__ h_out)  // [B, D]
{
    const int b  = blockIdx.y;
    const int j0 = blockIdx.x * JT;
    const int t  = threadIdx.x;
    const int jj = t & (JT - 1);   // 0..63  (lane within wave)
    const int iq = t >> 6;         // 0..3   (wave index = i-quarter)
    const int j  = j0 + jj;

    __shared__ float hs[D];
    __shared__ float partial[BLOCK];

    // Stage h[b,:] into LDS (coalesced load, broadcast reads later).
    for (int i = t; i < D; i += BLOCK) hs[i] = h_in[b * D + i];
    __syncthreads();

    // Each wave reduces its i-quarter; W reads coalesced across lanes (j).
    const float* w = W + (size_t)b * D * D + j;
    const int i_beg = iq * ICHUNK;
    float acc = 0.f;
#pragma unroll 8
    for (int i = i_beg; i < i_beg + ICHUNK; ++i) {
        acc = fmaf(hs[i], w[(size_t)i * D], acc);
    }

    partial[t] = acc;
    __syncthreads();

    if (t < JT) {
        float s = partial[t] + partial[t + 64] + partial[t + 128] + partial[t + 192];
        const int idx = b * D + j0 + t;
        s += bias[idx];
        if (mask[idx]) s = fmaxf(s, 0.f);
        h_out[idx] = s;
    }
}

extern "C" void kernel_launch(void* const* d_in, const int* in_sizes, int n_in,
                              void* d_out, int out_size, void* d_ws, size_t ws_size,
                              hipStream_t stream) {
    const float* x       = (const float*)d_in[0];  // [B, D]
    const float* weights = (const float*)d_in[1];  // [L, B, D, D]
    const float* biases  = (const float*)d_in[2];  // [L, B, D]
    const int*   masks   = (const int*)  d_in[3];  // [L, B, D]
    float* out = (float*)d_out;                    // [B, D]

    // Ping-pong h through workspace; final layer writes d_out.
    float* ws0 = (float*)d_ws;
    float* ws1 = ws0 + B * D;

    dim3 grid(D / JT, B);
    dim3 block(BLOCK);

    const float* hin = x;
    for (int l = 0; l < L; ++l) {
        float* hout = (l == L - 1) ? out : ((l & 1) ? ws1 : ws0);
        layer_kernel<<<grid, block, 0, stream>>>(
            hin,
            weights + (size_t)l * B * D * D,
            biases  + (size_t)l * B * D,
            masks   + (size_t)l * B * D,
            hout);
        hin = hout;
    }
}